// Round 1
// baseline (788.700 us; speedup 1.0000x reference)
//
#include <hip/hip_runtime.h>
#include <stdint.h>

#define S_TOK 4096
#define DIM   1024
#define NE    8
#define HID   4096

typedef __attribute__((ext_vector_type(4))) float f32x4;
typedef __attribute__((ext_vector_type(8))) short bf16x8;

static __device__ __forceinline__ ushort f2bf(float f) {
  uint u = __float_as_uint(f);
  u += 0x7FFFu + ((u >> 16) & 1u);
  return (ushort)(u >> 16);
}

static __device__ __forceinline__ double shfl_xor_d(double v, int off) {
  long long l = __double_as_longlong(v);
  int lo = (int)(l & 0xFFFFFFFFll), hi = (int)(l >> 32);
  lo = __shfl_xor(lo, off);
  hi = __shfl_xor(hi, off);
  return __longlong_as_double(((long long)hi << 32) | (unsigned int)lo);
}

// ---------------- Kernel 1: router (fp64) + x -> bf16 ----------------
// 1 wave per token. logits = gate_weight @ x + bias, softmax over experts.
__global__ __launch_bounds__(256) void router_kernel(
    const float* __restrict__ x, const float* __restrict__ gw,
    const float* __restrict__ bias, double* __restrict__ scoresd,
    ushort* __restrict__ xb)
{
  const int t = blockIdx.x * 4 + (threadIdx.x >> 6);
  const int lane = threadIdx.x & 63;
  double acc[NE];
#pragma unroll
  for (int e = 0; e < NE; ++e) acc[e] = 0.0;
  const float4* xrow = (const float4*)(x + (size_t)t * DIM);
  ushort* xbrow = xb + (size_t)t * DIM;
#pragma unroll
  for (int j = 0; j < 4; ++j) {
    const int c4 = j * 64 + lane;
    float4 xv = xrow[c4];
    ushort4 bv;
    bv.x = f2bf(xv.x); bv.y = f2bf(xv.y); bv.z = f2bf(xv.z); bv.w = f2bf(xv.w);
    ((ushort4*)xbrow)[c4] = bv;
#pragma unroll
    for (int e = 0; e < NE; ++e) {
      float4 g = ((const float4*)(gw + (size_t)e * DIM))[c4];
      acc[e] += (double)xv.x * g.x + (double)xv.y * g.y
              + (double)xv.z * g.z + (double)xv.w * g.w;
    }
  }
#pragma unroll
  for (int e = 0; e < NE; ++e) {
    double v = acc[e];
#pragma unroll
    for (int off = 32; off >= 1; off >>= 1) v += shfl_xor_d(v, off);
    acc[e] = v + (double)bias[e];
  }
  double m = acc[0];
#pragma unroll
  for (int e = 1; e < NE; ++e) m = (acc[e] > m) ? acc[e] : m;
  double den = 0.0;
#pragma unroll
  for (int e = 0; e < NE; ++e) { acc[e] = exp(acc[e] - m); den += acc[e]; }
  const double inv = 1.0 / den;
#pragma unroll
  for (int e = 0; e < NE; ++e)
    if (lane == e) scoresd[(size_t)e * S_TOK + t] = acc[e] * inv;
}

// ---------------- Kernel 2: global top-k select (single block) ----------------
// 64-bit radix-select of k-th largest over register-cached keys, then
// flat-index-ordered selection (replicates top_k tie semantics), building
// per-expert compacted token lists + gates + counts + bases.
__global__ __launch_bounds__(1024) void select_kernel(
    const double* __restrict__ scoresd, const int* __restrict__ capacity,
    int* __restrict__ counts, int* __restrict__ bases,
    int* __restrict__ lists, float* __restrict__ gates)
{
  __shared__ int sh_cnt;
  __shared__ unsigned long long sh_p;
  __shared__ int sh_r;
  __shared__ int wsum[16];
  __shared__ int sh_run;
  __shared__ int cnt_e[NE];
  const int tid = threadIdx.x, lane = tid & 63, wv = tid >> 6;
  const int k = S_TOK * capacity[0];

  unsigned long long key[32];
#pragma unroll
  for (int c = 0; c < 32; ++c)
    key[c] = (unsigned long long)__double_as_longlong(scoresd[c * 1024 + tid]);

  if (tid == 0) { sh_p = 0ull; sh_r = k; sh_run = 0; }
  if (tid < NE) cnt_e[tid] = 0;
  __syncthreads();

  // radix-select: find k-th largest key (scores are positive -> bit order = value order)
  for (int b = 63; b >= 0; --b) {
    if (tid == 0) sh_cnt = 0;
    __syncthreads();
    const unsigned long long p = sh_p;
    const unsigned long long mask = (~0ull) << b;
    const unsigned long long test = p | (1ull << b);
    int local = 0;
#pragma unroll
    for (int c = 0; c < 32; ++c) local += ((key[c] & mask) == test) ? 1 : 0;
#pragma unroll
    for (int off = 32; off >= 1; off >>= 1) local += __shfl_xor(local, off);
    if (lane == 0) atomicAdd(&sh_cnt, local);
    __syncthreads();
    if (tid == 0) {
      if (sh_r <= sh_cnt) sh_p |= (1ull << b); else sh_r -= sh_cnt;
    }
    __syncthreads();
  }
  const unsigned long long p = sh_p;

  // count strictly-greater
  if (tid == 0) sh_cnt = 0;
  __syncthreads();
  {
    int local = 0;
#pragma unroll
    for (int c = 0; c < 32; ++c) local += (key[c] > p) ? 1 : 0;
#pragma unroll
    for (int off = 32; off >= 1; off >>= 1) local += __shfl_xor(local, off);
    if (lane == 0) atomicAdd(&sh_cnt, local);
  }
  __syncthreads();
  const int need_eq = k - sh_cnt;

  // ordered selection over flat indices (chunks of 1024, block-wide scan of ties)
#pragma unroll
  for (int c = 0; c < 32; ++c) {
    const int i = c * 1024 + tid;
    const bool gt = key[c] > p;
    const bool eq = (key[c] == p);
    const unsigned long long bal = __ballot(eq);
    const int wpref = __popcll(bal & ((1ull << lane) - 1ull));
    if (lane == 0) wsum[wv] = __popcll(bal);
    __syncthreads();
    int wbase = 0;
    for (int w = 0; w < wv; ++w) wbase += wsum[w];
    const int rank = sh_run + wbase + wpref;
    if (gt || (eq && rank < need_eq)) {
      const int e = i >> 12;             // S_TOK = 4096 = 2^12
      const int s = i & (S_TOK - 1);
      const int slot = atomicAdd(&cnt_e[e], 1);
      lists[e * S_TOK + slot] = s;
      gates[e * S_TOK + slot] = (float)__longlong_as_double((long long)key[c]);
    }
    __syncthreads();
    if (tid == 0) {
      int tot = 0;
      for (int w = 0; w < 16; ++w) tot += wsum[w];
      sh_run += tot;
    }
    __syncthreads();
  }

  if (tid == 0) {
    int b0 = 0;
    for (int e = 0; e < NE; ++e) { counts[e] = cnt_e[e]; bases[e] = b0; b0 += cnt_e[e]; }
  }
}

// ---------------- Kernel 3: GEMM1  H = gelu(gather(X) @ W1 + b1) ----------------
// 128x128 tile, BK=32, 4 waves of 64x64 (4x4 16x16x32 bf16 MFMA fragments).
__global__ __launch_bounds__(256) void gemm1_kernel(
    const ushort* __restrict__ xb, const float* __restrict__ w1,
    const float* __restrict__ b1, const int* __restrict__ counts,
    const int* __restrict__ bases, const int* __restrict__ lists,
    ushort* __restrict__ hbuf)
{
  const int e = blockIdx.z;
  const int ne = counts[e];
  const int row0 = blockIdx.y * 128;
  if (row0 >= ne) return;
  const int n0 = blockIdx.x * 128;
  const int base = bases[e];

  __shared__ ushort Al[128 * 40];   // [row][k] bf16, +8 pad (row stride 80B)
  __shared__ ushort Bl[128 * 40];   // [hcol][k] bf16 (k-contiguous for B-frag)

  const int tid = threadIdx.x, lane = tid & 63, wid = tid >> 6;
  const int wm = wid >> 1, wn = wid & 1;

  // A staging: thread -> rows (tid>>2) and 64+(tid>>2), k-slot tid&3 (16B pieces)
  const int ar0 = tid >> 2, ksa = tid & 3;
  const int tr0 = min(row0 + ar0, ne - 1);
  const int tr1 = min(row0 + 64 + ar0, ne - 1);
  const ushort* aptr0 = xb + (size_t)lists[e * S_TOK + tr0] * DIM + ksa * 8;
  const ushort* aptr1 = xb + (size_t)lists[e * S_TOK + tr1] * DIM + ksa * 8;

  // B staging: thread -> h col (tid&127), k-slots (tid>>7) and (tid>>7)+2
  const int hb = tid & 127, ksb = tid >> 7;
  const float* wb = w1 + (size_t)e * DIM * HID + (size_t)(n0 + hb);

  f32x4 acc[4][4];
#pragma unroll
  for (int i = 0; i < 4; ++i)
#pragma unroll
    for (int j = 0; j < 4; ++j) acc[i][j] = (f32x4){0.f, 0.f, 0.f, 0.f};

  for (int kk = 0; kk < DIM; kk += 32) {
    int4 av0 = *(const int4*)(aptr0 + kk);
    int4 av1 = *(const int4*)(aptr1 + kk);
    float fa[8], fbv[8];
#pragma unroll
    for (int j = 0; j < 8; ++j) {
      fa[j]  = wb[(size_t)(kk + ksb * 8 + j) * HID];
      fbv[j] = wb[(size_t)(kk + (ksb + 2) * 8 + j) * HID];
    }
    union { ushort u[8]; int4 v; } p0, p1;
#pragma unroll
    for (int j = 0; j < 8; ++j) { p0.u[j] = f2bf(fa[j]); p1.u[j] = f2bf(fbv[j]); }
    __syncthreads();
    *(int4*)&Al[ar0 * 40 + ksa * 8] = av0;
    *(int4*)&Al[(64 + ar0) * 40 + ksa * 8] = av1;
    *(int4*)&Bl[hb * 40 + ksb * 8] = p0.v;
    *(int4*)&Bl[hb * 40 + (ksb + 2) * 8] = p1.v;
    __syncthreads();
    bf16x8 af[4], bf[4];
#pragma unroll
    for (int m = 0; m < 4; ++m)
      af[m] = *(const bf16x8*)&Al[(wm * 64 + m * 16 + (lane & 15)) * 40 + (lane >> 4) * 8];
#pragma unroll
    for (int n = 0; n < 4; ++n)
      bf[n] = *(const bf16x8*)&Bl[(wn * 64 + n * 16 + (lane & 15)) * 40 + (lane >> 4) * 8];
#pragma unroll
    for (int m = 0; m < 4; ++m)
#pragma unroll
      for (int n = 0; n < 4; ++n)
        acc[m][n] = __builtin_amdgcn_mfma_f32_16x16x32_bf16(af[m], bf[n], acc[m][n], 0, 0, 0);
  }

  const float* b1e = b1 + (size_t)e * HID + n0;
#pragma unroll
  for (int m = 0; m < 4; ++m) {
#pragma unroll
    for (int r = 0; r < 4; ++r) {
      const int row = wm * 64 + m * 16 + (lane >> 4) * 4 + r;
      if (row0 + row < ne) {
        const size_t hrow = (size_t)(base + row0 + row) * HID + n0;
#pragma unroll
        for (int n = 0; n < 4; ++n) {
          const int col = wn * 64 + n * 16 + (lane & 15);
          float v = acc[m][n][r] + b1e[col];
          // gelu(tanh approx) = v * sigmoid(1.5957691216*(v + 0.044715 v^3))
          float t = v + 0.044715f * v * v * v;
          float g = v / (1.0f + __expf(-1.5957691216f * t));
          hbuf[hrow + col] = f2bf(g);
        }
      }
    }
  }
}

// ---------------- Kernel 4: GEMM2  out[token] += gate * (H @ W2 + b2) ----------------
__global__ __launch_bounds__(256) void gemm2_kernel(
    const ushort* __restrict__ hbuf, const float* __restrict__ w2,
    const float* __restrict__ b2, const int* __restrict__ counts,
    const int* __restrict__ bases, const int* __restrict__ lists,
    const float* __restrict__ gates, float* __restrict__ out)
{
  const int e = blockIdx.z;
  const int ne = counts[e];
  const int row0 = blockIdx.y * 128;
  if (row0 >= ne) return;
  const int n0 = blockIdx.x * 128;
  const int base = bases[e];

  __shared__ ushort Al[128 * 40];
  __shared__ ushort Bl[128 * 40];

  const int tid = threadIdx.x, lane = tid & 63, wid = tid >> 6;
  const int wm = wid >> 1, wn = wid & 1;

  const int ar0 = tid >> 2, ksa = tid & 3;
  const size_t hr0 = (size_t)(base + min(row0 + ar0, ne - 1)) * HID;
  const size_t hr1 = (size_t)(base + min(row0 + 64 + ar0, ne - 1)) * HID;
  const ushort* aptr0 = hbuf + hr0 + ksa * 8;
  const ushort* aptr1 = hbuf + hr1 + ksa * 8;

  const int hb = tid & 127, ksb = tid >> 7;
  const float* wb = w2 + (size_t)e * HID * DIM + (size_t)(n0 + hb);

  f32x4 acc[4][4];
#pragma unroll
  for (int i = 0; i < 4; ++i)
#pragma unroll
    for (int j = 0; j < 4; ++j) acc[i][j] = (f32x4){0.f, 0.f, 0.f, 0.f};

  for (int kk = 0; kk < HID; kk += 32) {
    int4 av0 = *(const int4*)(aptr0 + kk);
    int4 av1 = *(const int4*)(aptr1 + kk);
    float fa[8], fbv[8];
#pragma unroll
    for (int j = 0; j < 8; ++j) {
      fa[j]  = wb[(size_t)(kk + ksb * 8 + j) * DIM];
      fbv[j] = wb[(size_t)(kk + (ksb + 2) * 8 + j) * DIM];
    }
    union { ushort u[8]; int4 v; } p0, p1;
#pragma unroll
    for (int j = 0; j < 8; ++j) { p0.u[j] = f2bf(fa[j]); p1.u[j] = f2bf(fbv[j]); }
    __syncthreads();
    *(int4*)&Al[ar0 * 40 + ksa * 8] = av0;
    *(int4*)&Al[(64 + ar0) * 40 + ksa * 8] = av1;
    *(int4*)&Bl[hb * 40 + ksb * 8] = p0.v;
    *(int4*)&Bl[hb * 40 + (ksb + 2) * 8] = p1.v;
    __syncthreads();
    bf16x8 af[4], bf[4];
#pragma unroll
    for (int m = 0; m < 4; ++m)
      af[m] = *(const bf16x8*)&Al[(wm * 64 + m * 16 + (lane & 15)) * 40 + (lane >> 4) * 8];
#pragma unroll
    for (int n = 0; n < 4; ++n)
      bf[n] = *(const bf16x8*)&Bl[(wn * 64 + n * 16 + (lane & 15)) * 40 + (lane >> 4) * 8];
#pragma unroll
    for (int m = 0; m < 4; ++m)
#pragma unroll
      for (int n = 0; n < 4; ++n)
        acc[m][n] = __builtin_amdgcn_mfma_f32_16x16x32_bf16(af[m], bf[n], acc[m][n], 0, 0, 0);
  }

  const float* b2e = b2 + (size_t)e * DIM + n0;
#pragma unroll
  for (int m = 0; m < 4; ++m) {
#pragma unroll
    for (int r = 0; r < 4; ++r) {
      const int row = wm * 64 + m * 16 + (lane >> 4) * 4 + r;
      if (row0 + row < ne) {
        const int tok = lists[e * S_TOK + row0 + row];
        const float gv = gates[e * S_TOK + row0 + row];
        float* orow = out + (size_t)tok * DIM + n0;
#pragma unroll
        for (int n = 0; n < 4; ++n) {
          const int col = wn * 64 + n * 16 + (lane & 15);
          const float v = gv * (acc[m][n][r] + b2e[col]);
          __hip_atomic_fetch_add(&orow[col], v, __ATOMIC_RELAXED, __HIP_MEMORY_SCOPE_AGENT);
        }
      }
    }
  }
}

extern "C" void kernel_launch(void* const* d_in, const int* in_sizes, int n_in,
                              void* d_out, int out_size, void* d_ws, size_t ws_size,
                              hipStream_t stream)
{
  const float* x    = (const float*)d_in[0];
  const float* gw   = (const float*)d_in[1];
  const float* bias = (const float*)d_in[2];
  const float* w1   = (const float*)d_in[3];
  const float* b1   = (const float*)d_in[4];
  const float* w2   = (const float*)d_in[5];
  const float* b2   = (const float*)d_in[6];
  const int*   cap  = (const int*)d_in[7];
  float* out = (float*)d_out;
  char* ws = (char*)d_ws;

  // workspace layout (~75 MB)
  ushort* xb      = (ushort*)(ws);                              // 8 MB   x in bf16
  ushort* hbuf    = (ushort*)(ws + (size_t)8  * (1 << 20));     // 64 MB  8192 x 4096 bf16
  double* scoresd = (double*)(ws + (size_t)72 * (1 << 20));     // 256 KB
  int*    lists   = (int*)   (ws + (size_t)73 * (1 << 20));     // 128 KB
  float*  gates   = (float*) (ws + (size_t)74 * (1 << 20));     // 128 KB
  int*    counts  = (int*)   (ws + (size_t)75 * (1 << 20));     // 8 ints
  int*    bases   = counts + 64;

  hipMemsetAsync(d_out, 0, (size_t)out_size * sizeof(float), stream);

  router_kernel<<<dim3(S_TOK / 4), 256, 0, stream>>>(x, gw, bias, scoresd, xb);
  select_kernel<<<dim3(1), 1024, 0, stream>>>(scoresd, cap, counts, bases, lists, gates);
  gemm1_kernel<<<dim3(HID / 128, 32, NE), 256, 0, stream>>>(xb, w1, b1, counts, bases, lists, hbuf);
  gemm2_kernel<<<dim3(DIM / 128, 32, NE), 256, 0, stream>>>(hbuf, w2, b2, counts, bases, lists, gates, out);
}

// Round 3
// 744.808 us; speedup vs baseline: 1.0589x; 1.0589x over previous
//
#include <hip/hip_runtime.h>
#include <stdint.h>

#define S_TOK 4096
#define DIM   1024
#define NE    8
#define HID   4096
#define HC    2048   // MLP hidden chunk (2 chunks keep workspace <= ~73 MB)

typedef __attribute__((ext_vector_type(4))) float f32x4;
typedef __attribute__((ext_vector_type(8))) short bf16x8;

static __device__ __forceinline__ ushort f2bf(float f) {
  uint u = __float_as_uint(f);
  u += 0x7FFFu + ((u >> 16) & 1u);
  return (ushort)(u >> 16);
}

static __device__ __forceinline__ void gload16(const ushort* g, ushort* l) {
  __builtin_amdgcn_global_load_lds(
      (const __attribute__((address_space(1))) void*)g,
      (__attribute__((address_space(3))) void*)l, 16, 0, 0);
}

static __device__ __forceinline__ double shfl_xor_d(double v, int off) {
  long long l = __double_as_longlong(v);
  int lo = (int)(l & 0xFFFFFFFFll), hi = (int)(l >> 32);
  lo = __shfl_xor(lo, off);
  hi = __shfl_xor(hi, off);
  return __longlong_as_double(((long long)hi << 32) | (unsigned int)lo);
}

// ------- Kernel 0: weight convert+transpose: read [r][c] f32 (rowStride), write [c][r] bf16 -------
__global__ __launch_bounds__(256) void wprep_kernel(
    const float* __restrict__ w, ushort* __restrict__ wT,
    int R, int rowStride, size_t eIn, size_t eOut)
{
  __shared__ float tile[64][65];
  const int e = blockIdx.z;
  const int c0 = blockIdx.x * 64, r0 = blockIdx.y * 64;
  const float* we = w + (size_t)e * eIn;
  ushort* wTe = wT + (size_t)e * eOut;
  const int t = threadIdx.x;
  const int rr = t >> 4, cq = t & 15;
#pragma unroll
  for (int p = 0; p < 4; ++p) {
    float4 v = *(const float4*)(we + (size_t)(r0 + p * 16 + rr) * rowStride + c0 + cq * 4);
    tile[p * 16 + rr][cq * 4 + 0] = v.x;
    tile[p * 16 + rr][cq * 4 + 1] = v.y;
    tile[p * 16 + rr][cq * 4 + 2] = v.z;
    tile[p * 16 + rr][cq * 4 + 3] = v.w;
  }
  __syncthreads();
#pragma unroll
  for (int p = 0; p < 4; ++p) {
    const int cc = p * 16 + rr;
    ushort4 o;
    o.x = f2bf(tile[cq * 4 + 0][cc]);
    o.y = f2bf(tile[cq * 4 + 1][cc]);
    o.z = f2bf(tile[cq * 4 + 2][cc]);
    o.w = f2bf(tile[cq * 4 + 3][cc]);
    *(ushort4*)(wTe + (size_t)(c0 + cc) * R + r0 + cq * 4) = o;
  }
}

// ---------------- Kernel 1: router (fp64) + x -> bf16 ----------------
__global__ __launch_bounds__(256) void router_kernel(
    const float* __restrict__ x, const float* __restrict__ gw,
    const float* __restrict__ bias, double* __restrict__ scoresd,
    ushort* __restrict__ xb)
{
  const int t = blockIdx.x * 4 + (threadIdx.x >> 6);
  const int lane = threadIdx.x & 63;
  double acc[NE];
#pragma unroll
  for (int e = 0; e < NE; ++e) acc[e] = 0.0;
  const float4* xrow = (const float4*)(x + (size_t)t * DIM);
  ushort* xbrow = xb + (size_t)t * DIM;
#pragma unroll
  for (int j = 0; j < 4; ++j) {
    const int c4 = j * 64 + lane;
    float4 xv = xrow[c4];
    ushort4 bv;
    bv.x = f2bf(xv.x); bv.y = f2bf(xv.y); bv.z = f2bf(xv.z); bv.w = f2bf(xv.w);
    ((ushort4*)xbrow)[c4] = bv;
#pragma unroll
    for (int e = 0; e < NE; ++e) {
      float4 g = ((const float4*)(gw + (size_t)e * DIM))[c4];
      acc[e] += (double)xv.x * g.x + (double)xv.y * g.y
              + (double)xv.z * g.z + (double)xv.w * g.w;
    }
  }
#pragma unroll
  for (int e = 0; e < NE; ++e) {
    double v = acc[e];
#pragma unroll
    for (int off = 32; off >= 1; off >>= 1) v += shfl_xor_d(v, off);
    acc[e] = v + (double)bias[e];
  }
  double m = acc[0];
#pragma unroll
  for (int e = 1; e < NE; ++e) m = (acc[e] > m) ? acc[e] : m;
  double den = 0.0;
#pragma unroll
  for (int e = 0; e < NE; ++e) { acc[e] = exp(acc[e] - m); den += acc[e]; }
  const double inv = 1.0 / den;
#pragma unroll
  for (int e = 0; e < NE; ++e)
    if (lane == e) scoresd[(size_t)e * S_TOK + t] = acc[e] * inv;
}

// ---------------- Kernel 2: global top-k select (single block) ----------------
__global__ __launch_bounds__(1024) void select_kernel(
    const double* __restrict__ scoresd, const int* __restrict__ capacity,
    int* __restrict__ counts, int* __restrict__ bases,
    int* __restrict__ lists, float* __restrict__ gates)
{
  __shared__ int sh_cnt;
  __shared__ unsigned long long sh_p;
  __shared__ int sh_r;
  __shared__ int wsum[16];
  __shared__ int sh_run;
  __shared__ int cnt_e[NE];
  const int tid = threadIdx.x, lane = tid & 63, wv = tid >> 6;
  const int k = S_TOK * capacity[0];

  unsigned long long key[32];
#pragma unroll
  for (int c = 0; c < 32; ++c)
    key[c] = (unsigned long long)__double_as_longlong(scoresd[c * 1024 + tid]);

  if (tid == 0) { sh_p = 0ull; sh_r = k; sh_run = 0; }
  if (tid < NE) cnt_e[tid] = 0;
  __syncthreads();

  for (int b = 63; b >= 0; --b) {
    if (tid == 0) sh_cnt = 0;
    __syncthreads();
    const unsigned long long p = sh_p;
    const unsigned long long mask = (~0ull) << b;
    const unsigned long long test = p | (1ull << b);
    int local = 0;
#pragma unroll
    for (int c = 0; c < 32; ++c) local += ((key[c] & mask) == test) ? 1 : 0;
#pragma unroll
    for (int off = 32; off >= 1; off >>= 1) local += __shfl_xor(local, off);
    if (lane == 0) atomicAdd(&sh_cnt, local);
    __syncthreads();
    if (tid == 0) {
      if (sh_r <= sh_cnt) sh_p |= (1ull << b); else sh_r -= sh_cnt;
    }
    __syncthreads();
  }
  const unsigned long long p = sh_p;

  if (tid == 0) sh_cnt = 0;
  __syncthreads();
  {
    int local = 0;
#pragma unroll
    for (int c = 0; c < 32; ++c) local += (key[c] > p) ? 1 : 0;
#pragma unroll
    for (int off = 32; off >= 1; off >>= 1) local += __shfl_xor(local, off);
    if (lane == 0) atomicAdd(&sh_cnt, local);
  }
  __syncthreads();
  const int need_eq = k - sh_cnt;

#pragma unroll
  for (int c = 0; c < 32; ++c) {
    const int i = c * 1024 + tid;
    const bool gt = key[c] > p;
    const bool eq = (key[c] == p);
    const unsigned long long bal = __ballot(eq);
    const int wpref = __popcll(bal & ((1ull << lane) - 1ull));
    if (lane == 0) wsum[wv] = __popcll(bal);
    __syncthreads();
    int wbase = 0;
    for (int w = 0; w < wv; ++w) wbase += wsum[w];
    const int rank = sh_run + wbase + wpref;
    if (gt || (eq && rank < need_eq)) {
      const int e = i >> 12;
      const int s = i & (S_TOK - 1);
      const int slot = atomicAdd(&cnt_e[e], 1);
      lists[e * S_TOK + slot] = s;
      gates[e * S_TOK + slot] = (float)__longlong_as_double((long long)key[c]);
    }
    __syncthreads();
    if (tid == 0) {
      int tot = 0;
      for (int w = 0; w < 16; ++w) tot += wsum[w];
      sh_run += tot;
    }
    __syncthreads();
  }

  if (tid == 0) {
    int b0 = 0;
    for (int e = 0; e < NE; ++e) { counts[e] = cnt_e[e]; bases[e] = b0; b0 += cnt_e[e]; }
  }
}

// ------- Kernel 3: GEMM1 chunk  H[:,hc0:hc0+HC] = gelu(gather(X) @ W1T_chunk + b1) -------
// m97 structure: 128x128 tile, BK=32, global_load_lds x4/thread, both-sides slot swizzle.
__global__ __launch_bounds__(256) void gemm1_kernel(
    const ushort* __restrict__ xb, const ushort* __restrict__ wT,
    const float* __restrict__ b1, const int* __restrict__ counts,
    const int* __restrict__ bases, const int* __restrict__ lists,
    ushort* __restrict__ hbuf, int hc0)
{
  const int e = blockIdx.z;
  const int ne = counts[e];
  const int row0 = blockIdx.y * 128;
  if (row0 >= ne) return;
  const int n0 = blockIdx.x * 128;   // within chunk [0, HC)
  const int base = bases[e];

  __shared__ ushort Al[128 * 32];
  __shared__ ushort Bl[128 * 32];

  const int tid = threadIdx.x, lane = tid & 63, w = tid >> 6;
  const int wm = w >> 1, wn = w & 1;
  const int r15 = lane & 15;

  const int sr = w * 32 + (lane >> 2);
  const int sslot = (lane & 3) ^ ((lane >> 3) & 3);
  const int tr0 = min(row0 + sr, ne - 1);
  const int tr1 = min(row0 + sr + 16, ne - 1);
  const ushort* ap0 = xb + (size_t)lists[e * S_TOK + tr0] * DIM + sslot * 8;
  const ushort* ap1 = xb + (size_t)lists[e * S_TOK + tr1] * DIM + sslot * 8;
  const ushort* wTe = wT + (size_t)e * HC * DIM;
  const ushort* bp0 = wTe + (size_t)(n0 + sr) * DIM + sslot * 8;
  const ushort* bp1 = wTe + (size_t)(n0 + sr + 16) * DIM + sslot * 8;
  ushort* la0 = &Al[w * 1024];
  ushort* la1 = &Al[w * 1024 + 512];
  ushort* lb0 = &Bl[w * 1024];
  ushort* lb1 = &Bl[w * 1024 + 512];

  const int slotr = ((lane >> 4) ^ ((lane >> 1) & 3)) * 8;

  f32x4 acc[4][4];
#pragma unroll
  for (int i = 0; i < 4; ++i)
#pragma unroll
    for (int j = 0; j < 4; ++j) acc[i][j] = (f32x4){0.f, 0.f, 0.f, 0.f};

  for (int kk = 0; kk < DIM; kk += 32) {
    __syncthreads();
    gload16(ap0 + kk, la0);
    gload16(ap1 + kk, la1);
    gload16(bp0 + kk, lb0);
    gload16(bp1 + kk, lb1);
    __syncthreads();
    bf16x8 af[4], bfr[4];
#pragma unroll
    for (int m = 0; m < 4; ++m)
      af[m] = *(const bf16x8*)&Al[(wm * 64 + m * 16 + r15) * 32 + slotr];
#pragma unroll
    for (int n = 0; n < 4; ++n)
      bfr[n] = *(const bf16x8*)&Bl[(wn * 64 + n * 16 + r15) * 32 + slotr];
#pragma unroll
    for (int m = 0; m < 4; ++m)
#pragma unroll
      for (int n = 0; n < 4; ++n)
        acc[m][n] = __builtin_amdgcn_mfma_f32_16x16x32_bf16(af[m], bfr[n], acc[m][n], 0, 0, 0);
  }

  const float* b1e = b1 + (size_t)e * HID + hc0 + n0;
#pragma unroll
  for (int m = 0; m < 4; ++m) {
#pragma unroll
    for (int r = 0; r < 4; ++r) {
      const int row = wm * 64 + m * 16 + (lane >> 4) * 4 + r;
      if (row0 + row < ne) {
        const size_t hrow = (size_t)(base + row0 + row) * HC + n0;
#pragma unroll
        for (int n = 0; n < 4; ++n) {
          const int col = wn * 64 + n * 16 + r15;
          float v = acc[m][n][r] + b1e[col];
          float t = v + 0.044715f * v * v * v;
          float g = v / (1.0f + __expf(-1.5957691216f * t));
          hbuf[hrow + col] = f2bf(g);
        }
      }
    }
  }
}

// ------- Kernel 4: GEMM2 chunk  out[token] += gate * (H_chunk @ W2T_chunk [+ b2]) -------
__global__ __launch_bounds__(256) void gemm2_kernel(
    const ushort* __restrict__ hbuf, const ushort* __restrict__ wT,
    const float* __restrict__ b2, const int* __restrict__ counts,
    const int* __restrict__ bases, const int* __restrict__ lists,
    const float* __restrict__ gates, float* __restrict__ out, int addBias)
{
  const int e = blockIdx.z;
  const int ne = counts[e];
  const int row0 = blockIdx.y * 128;
  if (row0 >= ne) return;
  const int n0 = blockIdx.x * 128;
  const int base = bases[e];

  __shared__ ushort Al[128 * 32];
  __shared__ ushort Bl[128 * 32];

  const int tid = threadIdx.x, lane = tid & 63, w = tid >> 6;
  const int wm = w >> 1, wn = w & 1;
  const int r15 = lane & 15;

  const int sr = w * 32 + (lane >> 2);
  const int sslot = (lane & 3) ^ ((lane >> 3) & 3);
  const int tr0 = min(row0 + sr, ne - 1);
  const int tr1 = min(row0 + sr + 16, ne - 1);
  const ushort* ap0 = hbuf + (size_t)(base + tr0) * HC + sslot * 8;
  const ushort* ap1 = hbuf + (size_t)(base + tr1) * HC + sslot * 8;
  const ushort* wTe = wT + (size_t)e * DIM * HC;
  const ushort* bp0 = wTe + (size_t)(n0 + sr) * HC + sslot * 8;
  const ushort* bp1 = wTe + (size_t)(n0 + sr + 16) * HC + sslot * 8;
  ushort* la0 = &Al[w * 1024];
  ushort* la1 = &Al[w * 1024 + 512];
  ushort* lb0 = &Bl[w * 1024];
  ushort* lb1 = &Bl[w * 1024 + 512];

  const int slotr = ((lane >> 4) ^ ((lane >> 1) & 3)) * 8;

  f32x4 acc[4][4];
#pragma unroll
  for (int i = 0; i < 4; ++i)
#pragma unroll
    for (int j = 0; j < 4; ++j) acc[i][j] = (f32x4){0.f, 0.f, 0.f, 0.f};

  for (int kk = 0; kk < HC; kk += 32) {
    __syncthreads();
    gload16(ap0 + kk, la0);
    gload16(ap1 + kk, la1);
    gload16(bp0 + kk, lb0);
    gload16(bp1 + kk, lb1);
    __syncthreads();
    bf16x8 af[4], bfr[4];
#pragma unroll
    for (int m = 0; m < 4; ++m)
      af[m] = *(const bf16x8*)&Al[(wm * 64 + m * 16 + r15) * 32 + slotr];
#pragma unroll
    for (int n = 0; n < 4; ++n)
      bfr[n] = *(const bf16x8*)&Bl[(wn * 64 + n * 16 + r15) * 32 + slotr];
#pragma unroll
    for (int m = 0; m < 4; ++m)
#pragma unroll
      for (int n = 0; n < 4; ++n)
        acc[m][n] = __builtin_amdgcn_mfma_f32_16x16x32_bf16(af[m], bfr[n], acc[m][n], 0, 0, 0);
  }

  const float* b2e = b2 + (size_t)e * DIM + n0;
#pragma unroll
  for (int m = 0; m < 4; ++m) {
#pragma unroll
    for (int r = 0; r < 4; ++r) {
      const int row = wm * 64 + m * 16 + (lane >> 4) * 4 + r;
      if (row0 + row < ne) {
        const int tok = lists[e * S_TOK + row0 + row];
        const float gv = gates[e * S_TOK + row0 + row];
        float* orow = out + (size_t)tok * DIM + n0;
#pragma unroll
        for (int n = 0; n < 4; ++n) {
          const int col = wn * 64 + n * 16 + r15;
          const float bb = addBias ? b2e[col] : 0.f;
          const float v = gv * (acc[m][n][r] + bb);
          __hip_atomic_fetch_add(&orow[col], v, __ATOMIC_RELAXED, __HIP_MEMORY_SCOPE_AGENT);
        }
      }
    }
  }
}

extern "C" void kernel_launch(void* const* d_in, const int* in_sizes, int n_in,
                              void* d_out, int out_size, void* d_ws, size_t ws_size,
                              hipStream_t stream)
{
  const float* x    = (const float*)d_in[0];
  const float* gw   = (const float*)d_in[1];
  const float* bias = (const float*)d_in[2];
  const float* w1   = (const float*)d_in[3];
  const float* b1   = (const float*)d_in[4];
  const float* w2   = (const float*)d_in[5];
  const float* b2   = (const float*)d_in[6];
  const int*   cap  = (const int*)d_in[7];
  float* out = (float*)d_out;
  char* ws = (char*)d_ws;

  // workspace layout (~73 MB, under the 75.25 MB proven safe in round 1)
  ushort* xb      = (ushort*)(ws);                                // 8 MB
  ushort* hbuf    = (ushort*)(ws + (size_t)8  * (1 << 20));       // 32 MB  (8192 x 2048 bf16)
  ushort* wT      = (ushort*)(ws + (size_t)40 * (1 << 20));       // 32 MB  (per-chunk weights)
  double* scoresd = (double*)(ws + (size_t)72 * (1 << 20));       // 256 KB
  int*    lists   = (int*)   (ws + (size_t)72 * (1 << 20) + 262144);
  float*  gates   = (float*) (ws + (size_t)72 * (1 << 20) + 262144 + 131072);
  int*    counts  = (int*)   (ws + (size_t)72 * (1 << 20) + 262144 + 262144);
  int*    bases   = counts + 64;

  hipMemsetAsync(d_out, 0, (size_t)out_size * sizeof(float), stream);

  router_kernel<<<dim3(S_TOK / 4), 256, 0, stream>>>(x, gw, bias, scoresd, xb);
  select_kernel<<<dim3(1), 1024, 0, stream>>>(scoresd, cap, counts, bases, lists, gates);

  for (int chunk = 0; chunk < 2; ++chunk) {
    const int hc0 = chunk * HC;
    // w1[:, :, hc0:hc0+HC]  [D][HC] f32 -> wT [HC][D] bf16
    wprep_kernel<<<dim3(HC / 64, DIM / 64, NE), 256, 0, stream>>>(
        w1 + hc0, wT, DIM, HID, (size_t)DIM * HID, (size_t)HC * DIM);
    gemm1_kernel<<<dim3(HC / 128, 32, NE), 256, 0, stream>>>(
        xb, wT, b1, counts, bases, lists, hbuf, hc0);
    // w2[:, hc0:hc0+HC, :]  [HC][D] f32 -> wT [D][HC] bf16 (reuses buffer)
    wprep_kernel<<<dim3(DIM / 64, HC / 64, NE), 256, 0, stream>>>(
        w2 + (size_t)hc0 * DIM, wT, HC, DIM, (size_t)HID * DIM, (size_t)DIM * HC);
    gemm2_kernel<<<dim3(DIM / 128, 32, NE), 256, 0, stream>>>(
        hbuf, wT, b2, counts, bases, lists, gates, out, chunk == 0 ? 1 : 0);
  }
}